// Round 18
// baseline (32.482 us; speedup 1.0000x reference)
//
#include <hip/hip_runtime.h>

#define NN 1024

typedef __attribute__((ext_vector_type(8))) short short8;
typedef __attribute__((ext_vector_type(4))) float floatx4;
typedef __attribute__((ext_vector_type(4))) unsigned int uint4v;
typedef _Float16 half2v __attribute__((ext_vector_type(2)));
typedef _Float16 half8 __attribute__((ext_vector_type(8)));

// ---- ws layout (bytes) ----
#define R2_OFF   0u          // u32 R2[128][1024]: pk-f16 (R~_{2hp}, R~_{2hp+1}) per i
#define CT_OFF   524288u     // u32 Ct[32][1024][4]: pk-f16 Cn pairs, [hpg][j][hp&3]

__device__ __forceinline__ unsigned short f2bf(float x) {  // RNE f32->bf16
  unsigned u = __float_as_uint(x);
  return (unsigned short)((u + 0x7FFFu + ((u >> 16) & 1u)) >> 16);
}

__device__ __forceinline__ unsigned int pkf16(float a, float b) {
  unsigned int lo = (unsigned int)__builtin_bit_cast(unsigned short, (_Float16)a);
  unsigned int hi = (unsigned int)__builtin_bit_cast(unsigned short, (_Float16)b);
  return lo | (hi << 16);
}

__device__ __forceinline__ void dot2acc(unsigned int a, unsigned int b, float& acc) {
#if __has_builtin(__builtin_amdgcn_fdot2)
  acc = __builtin_amdgcn_fdot2(__builtin_bit_cast(half2v, a),
                               __builtin_bit_cast(half2v, b), acc, false);
#else
  asm("v_dot2_f32_f16 %0, %1, %2, %0" : "+v"(acc) : "v"(a), "v"(b));
#endif
}

// ---------------- k1: fused prep + fc1 GEMM (bf16 MFMA) -> pk-f16 R2 / Ct ----------------
// (byte-identical to r11 -- measured 1.9 us in r14 rep-diagnostic)
__global__ __launch_bounds__(256) void k1_fused(const float* __restrict__ z,
    const float* __restrict__ W1, const float* __restrict__ b1,
    const float* __restrict__ W2, char* __restrict__ ws) {
  __shared__ unsigned short zsh[16][272];
  __shared__ unsigned short wsh[4][16][272];
  __shared__ float tile[4][16][17];
  unsigned int* R2 = (unsigned int*)(ws + R2_OFF);
  unsigned int* Ct = (unsigned int*)(ws + CT_OFF);

  const int t = threadIdx.x;
  const int l = t & 63, w = t >> 6;
  const int i0 = blockIdx.x * 16;
  const int tid = blockIdx.y * 4 + w;
  const int q0 = tid * 16;
  const bool topR = q0 < 256;
  const int h0 = q0 & 255;
  const int off = topR ? 0 : 256;

  #pragma unroll
  for (int k = 0; k < 4; ++k) {
    const int f = t + k * 256;
    const int r = f >> 6, c4 = f & 63;
    const float4 v = *(const float4*)(z + (i0 + r) * 256 + c4 * 4);
    ushort4 u;
    u.x = f2bf(v.x); u.y = f2bf(v.y); u.z = f2bf(v.z); u.w = f2bf(v.w);
    *(ushort4*)&zsh[r][c4 * 4] = u;
  }
  #pragma unroll 4
  for (int r = 0; r < 16; ++r) {
    const int h = h0 + r;
    const float wa = fabsf(W2[h]);
    const float sc = topR ? wa : -wa;
    const float4 v = *(const float4*)(W1 + h * 512 + off + l * 4);
    ushort4 u;
    u.x = f2bf(v.x * sc); u.y = f2bf(v.y * sc);
    u.z = f2bf(v.z * sc); u.w = f2bf(v.w * sc);
    *(ushort4*)&wsh[w][r][l * 4] = u;
  }
  __syncthreads();

  floatx4 acc = {0.f, 0.f, 0.f, 0.f};
  const int fr = l & 15, fg = (l >> 4) * 8;
  #pragma unroll
  for (int kk = 0; kk < 8; ++kk) {
    const short8 a  = *(const short8*)&zsh[fr][fg + kk * 32];
    const short8 bb = *(const short8*)&wsh[w][fr][fg + kk * 32];
    acc = __builtin_amdgcn_mfma_f32_16x16x32_bf16(a, bb, acc, 0, 0, 0);
  }

  const int col = l & 15, r0 = (l >> 4) * 4;
  float bias = 0.f;
  if (topR) {
    const int h = q0 + col;
    bias = b1[h] * fabsf(W2[h]);
  }
  #pragma unroll
  for (int q = 0; q < 4; ++q) tile[w][r0 + q][col] = acc[q] + bias;
  __syncthreads();
  const int il = l & 15, g2 = l >> 4;
  if (topR) {
    #pragma unroll
    for (int e = 0; e < 2; ++e) {
      const int qc = g2 * 4 + e * 2;
      const unsigned int pk = pkf16(tile[w][il][qc], tile[w][il][qc + 1]);
      R2[((q0 >> 1) + g2 * 2 + e) * 1024 + (i0 + il)] = pk;
    }
  } else {
    const unsigned int pk0 = pkf16(tile[w][il][g2 * 4 + 0], tile[w][il][g2 * 4 + 1]);
    const unsigned int pk1 = pkf16(tile[w][il][g2 * 4 + 2], tile[w][il][g2 * 4 + 3]);
    const int hpg = ((q0 - 256) >> 3) + (g2 >> 1);
    unsigned int* dst = Ct + (hpg * 1024 + (i0 + il)) * 4 + (g2 & 1) * 2;
    dst[0] = pk0; dst[1] = pk1;
  }
}

// ---------------- k2: pairwise decode via pkmax + f16-MFMA contraction (FULL 8 chunks) ----------------
// grid (64,16) = 1024 blocks, 256 thr = 4 waves (~105 VGPR -> 4 waves/SIMD). Wave w owns
// i-rows [i0+4w, +4) x 64 j x ALL 256 h. Per chunk c (0..7 -- r17 bug: only 0..3 = half of H)
// and j-group g (0..15): lane l = A-row p = l&15 -> (iloc=p>>2, jloc=p&3), k-group kg = l>>4:
//   cv: GLOBAL uint4v read of Ct[hpg=c*4+kg][j0+4g+jloc] (L2-resident; LDS-staging C would
//       cost 128 ds_read_b128/wave ~ 12us of LDS pipe -- global is the cheaper path)
//   4x v_pk_max_f16(Rf, cv) -> A-frag; 1x mfma_f32_16x16x32_f16(A, B=s_h, acc[g]).
// D columns replicated (B rows identical) -> lane holds rows (l>>4)*4+reg of v_g[p].
__global__ __launch_bounds__(256) void k2_mfma(const unsigned int* __restrict__ R2,
    const unsigned int* __restrict__ Ct, const float* __restrict__ W2,
    const float* __restrict__ b2v, float* __restrict__ out) {
  __shared__ unsigned int Rl[16][144];   // [i_loc][hp], 9.2 KB
  __shared__ unsigned int MulS[128];     // 0.5 KB
  __shared__ float kvp[4][4][17];        // [jwave][quarter][jj]
  __shared__ float ebuf[4][4][68];       // [wave][i_s][j]
  const int t = threadIdx.x;
  const int l = t & 63, w = t >> 6;
  const int i0 = blockIdx.x * 16, j0 = blockIdx.y * 64;

  if (t < 128) {
    const unsigned int s0 = (W2[2 * t]     > 0.f) ? 0x3C00u : 0xBC00u;
    const unsigned int s1 = (W2[2 * t + 1] > 0.f) ? 0x3C00u : 0xBC00u;
    MulS[t] = s0 | (s1 << 16);
  }
  // stage Rl transposed: Rl[i][hp] = R2[hp][i0+i]
  #pragma unroll
  for (int k = 0; k < 8; ++k) {
    const int n = k * 256 + t;
    Rl[n & 15][n >> 4] = R2[(n >> 4) * 1024 + i0 + (n & 15)];
  }
  __syncthreads();

  // kv[j] = sum_h s_h * Cn[j][h]: lane j = j0 + w*16 + (l&15), quarter q = l>>4
  {
    const int jj = l & 15, q = l >> 4;
    float kp = 0.f;
    #pragma unroll
    for (int gg = 0; gg < 8; ++gg) {
      const int hpg = q * 8 + gg;
      const uint4v cv = *(const uint4v*)(Ct + (hpg * 1024 + j0 + w * 16 + jj) * 4);
      const uint4v mv = *(const uint4v*)&MulS[hpg * 4];
      dot2acc(cv.x, mv.x, kp); dot2acc(cv.y, mv.y, kp);
      dot2acc(cv.z, mv.z, kp); dot2acc(cv.w, mv.w, kp);
    }
    kvp[w][q][jj] = kp;
  }

  const int kg = l >> 4;
  const int iloc = (l & 15) >> 2;
  const int jloc = l & 3;
  const unsigned int* crow = Ct + (kg * 1024 + j0 + jloc) * 4;  // + c*16384 + g*16

  floatx4 acc[16] = {};                  // static idx via full unroll (rule #20)
  #pragma unroll
  for (int c = 0; c < 8; ++c) {          // 8 chunks x 32 h = ALL 256 h
    const uint4v Rf = *(const uint4v*)&Rl[w * 4 + iloc][c * 16 + kg * 4];
    const uint4v Bf = *(const uint4v*)&MulS[c * 16 + kg * 4];
    #pragma unroll
    for (int g = 0; g < 16; ++g) {
      const uint4v cv = *(const uint4v*)(crow + c * 16384 + g * 16);
      unsigned int m0, m1, m2, m3;
      asm("v_pk_max_f16 %0, %1, %2" : "=v"(m0) : "v"(Rf.x), "v"(cv.x));
      asm("v_pk_max_f16 %0, %1, %2" : "=v"(m1) : "v"(Rf.y), "v"(cv.y));
      asm("v_pk_max_f16 %0, %1, %2" : "=v"(m2) : "v"(Rf.z), "v"(cv.z));
      asm("v_pk_max_f16 %0, %1, %2" : "=v"(m3) : "v"(Rf.w), "v"(cv.w));
      uint4v av;
      av.x = m0; av.y = m1; av.z = m2; av.w = m3;
      acc[g] = __builtin_amdgcn_mfma_f32_16x16x32_f16(
          __builtin_bit_cast(half8, av), __builtin_bit_cast(half8, Bf),
          acc[g], 0, 0, 0);
    }
  }

  // redistribute D (columns replicated): lane with (l&15)==g holds v_g rows (l>>4)*4+reg
  #pragma unroll
  for (int g = 0; g < 16; ++g) {
    if ((l & 15) == g)
      *(floatx4*)&ebuf[w][l >> 4][g * 4] = acc[g];
  }
  __syncthreads();

  const int lw = l >> 4, jj = l & 15;
  const float kvl = kvp[lw][0][jj] + kvp[lw][1][jj] + kvp[lw][2][jj] + kvp[lw][3][jj];
  const float base = b2v[0] - kvl;
  #pragma unroll
  for (int s = 0; s < 4; ++s) {
    const float x = ebuf[w][s][l] + base;
    out[(i0 + w * 4 + s) * NN + j0 + l] = 1.f / (1.f + __expf(-x));
  }
}

extern "C" void kernel_launch(void* const* d_in, const int* in_sizes, int n_in,
                              void* d_out, int out_size, void* d_ws, size_t ws_size,
                              hipStream_t stream) {
  const float* z  = (const float*)d_in[0];
  const float* W1 = (const float*)d_in[1];
  const float* b1 = (const float*)d_in[2];
  const float* W2 = (const float*)d_in[3];
  const float* b2 = (const float*)d_in[4];
  float* out = (float*)d_out;
  char* ws = (char*)d_ws;

  k1_fused<<<dim3(64, 8), 256, 0, stream>>>(z, W1, b1, W2, ws);
  k2_mfma<<<dim3(64, 16), 256, 0, stream>>>(
      (const unsigned int*)(ws + R2_OFF), (const unsigned int*)(ws + CT_OFF),
      W2, b2, out);
}

// Round 19
// 24.387 us; speedup vs baseline: 1.3319x; 1.3319x over previous
//
#include <hip/hip_runtime.h>

#define NN 1024

typedef __attribute__((ext_vector_type(8))) short short8;
typedef __attribute__((ext_vector_type(4))) float floatx4;
typedef __attribute__((ext_vector_type(4))) unsigned int uint4v;
typedef _Float16 half2v __attribute__((ext_vector_type(2)));

// ---- ws layout (bytes) ----
#define R2_OFF   0u          // u32 R2[128][1024]: pk-f16 (R~_{2hp}, R~_{2hp+1}) per i
#define CT_OFF   524288u     // u32 Ct[32][1024][4]: pk-f16 Cn pairs, [hpg][j][hp&3]

__device__ __forceinline__ unsigned short f2bf(float x) {  // RNE f32->bf16
  unsigned u = __float_as_uint(x);
  return (unsigned short)((u + 0x7FFFu + ((u >> 16) & 1u)) >> 16);
}

__device__ __forceinline__ unsigned int pkf16(float a, float b) {
  unsigned int lo = (unsigned int)__builtin_bit_cast(unsigned short, (_Float16)a);
  unsigned int hi = (unsigned int)__builtin_bit_cast(unsigned short, (_Float16)b);
  return lo | (hi << 16);
}

__device__ __forceinline__ void dot2acc(unsigned int a, unsigned int b, float& acc) {
#if __has_builtin(__builtin_amdgcn_fdot2)
  acc = __builtin_amdgcn_fdot2(__builtin_bit_cast(half2v, a),
                               __builtin_bit_cast(half2v, b), acc, false);
#else
  asm("v_dot2_f32_f16 %0, %1, %2, %0" : "+v"(acc) : "v"(a), "v"(b));
#endif
}

// core: acc += dot2( pk_max(r, c), mul )
__device__ __forceinline__ void pkmaxdot(unsigned int r, unsigned int c,
                                         unsigned int mul, float& acc) {
  unsigned int m;
  asm("v_pk_max_f16 %0, %1, %2" : "=v"(m) : "v"(r), "v"(c));
  dot2acc(m, mul, acc);
}

// ---------------- k1: fused prep + fc1 GEMM (bf16 MFMA) -> pk-f16 R2 / Ct ----------------
// (byte-identical to r11 -- measured 1.9 us in r14 rep-diagnostic)
__global__ __launch_bounds__(256) void k1_fused(const float* __restrict__ z,
    const float* __restrict__ W1, const float* __restrict__ b1,
    const float* __restrict__ W2, char* __restrict__ ws) {
  __shared__ unsigned short zsh[16][272];
  __shared__ unsigned short wsh[4][16][272];
  __shared__ float tile[4][16][17];
  unsigned int* R2 = (unsigned int*)(ws + R2_OFF);
  unsigned int* Ct = (unsigned int*)(ws + CT_OFF);

  const int t = threadIdx.x;
  const int l = t & 63, w = t >> 6;
  const int i0 = blockIdx.x * 16;
  const int tid = blockIdx.y * 4 + w;
  const int q0 = tid * 16;
  const bool topR = q0 < 256;
  const int h0 = q0 & 255;
  const int off = topR ? 0 : 256;

  #pragma unroll
  for (int k = 0; k < 4; ++k) {
    const int f = t + k * 256;
    const int r = f >> 6, c4 = f & 63;
    const float4 v = *(const float4*)(z + (i0 + r) * 256 + c4 * 4);
    ushort4 u;
    u.x = f2bf(v.x); u.y = f2bf(v.y); u.z = f2bf(v.z); u.w = f2bf(v.w);
    *(ushort4*)&zsh[r][c4 * 4] = u;
  }
  #pragma unroll 4
  for (int r = 0; r < 16; ++r) {
    const int h = h0 + r;
    const float wa = fabsf(W2[h]);
    const float sc = topR ? wa : -wa;
    const float4 v = *(const float4*)(W1 + h * 512 + off + l * 4);
    ushort4 u;
    u.x = f2bf(v.x * sc); u.y = f2bf(v.y * sc);
    u.z = f2bf(v.z * sc); u.w = f2bf(v.w * sc);
    *(ushort4*)&wsh[w][r][l * 4] = u;
  }
  __syncthreads();

  floatx4 acc = {0.f, 0.f, 0.f, 0.f};
  const int fr = l & 15, fg = (l >> 4) * 8;
  #pragma unroll
  for (int kk = 0; kk < 8; ++kk) {
    const short8 a  = *(const short8*)&zsh[fr][fg + kk * 32];
    const short8 bb = *(const short8*)&wsh[w][fr][fg + kk * 32];
    acc = __builtin_amdgcn_mfma_f32_16x16x32_bf16(a, bb, acc, 0, 0, 0);
  }

  const int col = l & 15, r0 = (l >> 4) * 4;
  float bias = 0.f;
  if (topR) {
    const int h = q0 + col;
    bias = b1[h] * fabsf(W2[h]);
  }
  #pragma unroll
  for (int q = 0; q < 4; ++q) tile[w][r0 + q][col] = acc[q] + bias;
  __syncthreads();
  const int il = l & 15, g2 = l >> 4;
  if (topR) {
    #pragma unroll
    for (int e = 0; e < 2; ++e) {
      const int qc = g2 * 4 + e * 2;
      const unsigned int pk = pkf16(tile[w][il][qc], tile[w][il][qc + 1]);
      R2[((q0 >> 1) + g2 * 2 + e) * 1024 + (i0 + il)] = pk;
    }
  } else {
    const unsigned int pk0 = pkf16(tile[w][il][g2 * 4 + 0], tile[w][il][g2 * 4 + 1]);
    const unsigned int pk1 = pkf16(tile[w][il][g2 * 4 + 2], tile[w][il][g2 * 4 + 3]);
    const int hpg = ((q0 - 256) >> 3) + (g2 >> 1);
    unsigned int* dst = Ct + (hpg * 1024 + (i0 + il)) * 4 + (g2 & 1) * 2;
    dst[0] = pk0; dst[1] = pk1;
  }
}

// ---------------- k2: r11 core, occupancy-unlocked ----------------
// Tile 16i x 64j, grid (64,16) = 1024 blocks (4/CU), 256 thr = 4 waves.
// r14 diagnostic: old k2 capped at 2 waves/SIMD by THREE limits (VGPR 132 > 128,
// LDS 51KB, grid 512). Fixes: half tile (acc 32->16 regs, drop 3rd prefetch buf
// -> ~90 VGPR), part[] aliases Rl's LDS pool (live ranges disjoint; one added
// barrier) -> ~18 KB, grid 1024. Target: 4 waves/SIMD, VALUBusy 46 -> ~80%.
__global__ __launch_bounds__(256) void k2_pair(const unsigned int* __restrict__ R2,
    const unsigned int* __restrict__ Ct, const float* __restrict__ W2,
    const float* __restrict__ b2v, float* __restrict__ out) {
  __shared__ __align__(16) char pool[16640];   // union: Rl[128][16] u32 (8KB) / part[4][16][65] f32 (16.6KB)
  unsigned int (*Rl)[16] = (unsigned int (*)[16])pool;
  float (*part)[16][65] = (float (*)[16][65])pool;
  __shared__ float partkv[4][64];
  __shared__ unsigned int MulS[128];
  const int t = threadIdx.x;
  const int lane = t & 63, w = t >> 6;
  const int li = lane >> 4, lj = lane & 15;
  const int i0 = blockIdx.x * 16, j0 = blockIdx.y * 64;

  if (t < 128) {
    const unsigned int s0 = (W2[2 * t]     > 0.f) ? 0x3C00u : 0xBC00u;
    const unsigned int s1 = (W2[2 * t + 1] > 0.f) ? 0x3C00u : 0xBC00u;
    MulS[t] = s0 | (s1 << 16);
  }
  // stage Rl: 2048 u32, 8 per thread, coalesced in 16-lane groups
  #pragma unroll
  for (int k = 0; k < 8; ++k) {
    const int n = k * 256 + t;
    Rl[n >> 4][n & 15] = R2[(n >> 4) * 1024 + i0 + (n & 15)];
  }
  __syncthreads();

  const int hbase = w * 8;                 // this wave's hpg range [8w, 8w+8)
  float acc[4][4] = {};
  float kvacc[4] = {};

#define LOADC(BUF, MQ, G) do { \
    _Pragma("unroll") \
    for (int jj = 0; jj < 4; ++jj) \
      BUF[jj] = *(const uint4v*)(Ct + (((hbase + (G)) * 1024) + j0 + lj + 16 * jj) * 4); \
    MQ = *(const uint4v*)&MulS[(hbase + (G)) * 4]; \
  } while (0)

#define COMPG(BUF, MQ, G) do { \
    _Pragma("unroll") \
    for (int hp2 = 0; hp2 < 4; ++hp2) { \
      const int hp = (hbase + (G)) * 4 + hp2; \
      const uint4v ra = *(const uint4v*)&Rl[hp][li * 4]; \
      const unsigned int mu = MQ[hp2]; \
      _Pragma("unroll") \
      for (int jj = 0; jj < 4; ++jj) { \
        const unsigned int c = BUF[jj][hp2]; \
        dot2acc(c, mu, kvacc[jj]); \
        _Pragma("unroll") \
        for (int ii = 0; ii < 4; ++ii) pkmaxdot(ra[ii], c, mu, acc[ii][jj]); \
      } \
    } \
  } while (0)

  {
    uint4v A[4], B[4];
    uint4v MA, MB;
    LOADC(A, MA, 0); LOADC(B, MB, 1);
    COMPG(A, MA, 0); LOADC(A, MA, 2);
    COMPG(B, MB, 1); LOADC(B, MB, 3);
    COMPG(A, MA, 2); LOADC(A, MA, 4);
    COMPG(B, MB, 3); LOADC(B, MB, 5);
    COMPG(A, MA, 4); LOADC(A, MA, 6);
    COMPG(B, MB, 5); LOADC(B, MB, 7);
    COMPG(A, MA, 6);
    COMPG(B, MB, 7);
  }
#undef LOADC
#undef COMPG

  __syncthreads();                         // union hazard: all Rl reads done before part writes

  #pragma unroll
  for (int ii = 0; ii < 4; ++ii)
    #pragma unroll
    for (int jj = 0; jj < 4; ++jj)
      part[w][li * 4 + ii][lj + 16 * jj] = acc[ii][jj];
  if (li == 0) {
    #pragma unroll
    for (int jj = 0; jj < 4; ++jj) partkv[w][lj + 16 * jj] = kvacc[jj];
  }
  __syncthreads();

  // combine + sigmoid: 256 threads x 4 outputs
  const int jl = t & 63, ib = (t >> 6) * 4;
  const float kvt = partkv[0][jl] + partkv[1][jl] + partkv[2][jl] + partkv[3][jl];
  const float base = b2v[0] - kvt;         // Kv[j] = b2 - sum_h s*Cn
  #pragma unroll
  for (int u = 0; u < 4; ++u) {
    const int il = ib + u;
    const float x = part[0][il][jl] + part[1][il][jl] +
                    part[2][il][jl] + part[3][il][jl] + base;
    out[(i0 + il) * NN + j0 + jl] = 1.f / (1.f + __expf(-x));
  }
}

extern "C" void kernel_launch(void* const* d_in, const int* in_sizes, int n_in,
                              void* d_out, int out_size, void* d_ws, size_t ws_size,
                              hipStream_t stream) {
  const float* z  = (const float*)d_in[0];
  const float* W1 = (const float*)d_in[1];
  const float* b1 = (const float*)d_in[2];
  const float* W2 = (const float*)d_in[3];
  const float* b2 = (const float*)d_in[4];
  float* out = (float*)d_out;
  char* ws = (char*)d_ws;

  k1_fused<<<dim3(64, 8), 256, 0, stream>>>(z, W1, b1, W2, ws);
  k2_pair<<<dim3(64, 16), 256, 0, stream>>>(
      (const unsigned int*)(ws + R2_OFF), (const unsigned int*)(ws + CT_OFF),
      W2, b2, out);
}